// Round 7
// baseline (378.080 us; speedup 1.0000x reference)
//
#include <hip/hip_runtime.h>

// N=50000, E=400000, D=128, DE=64, H=8
#define D 128
#define DE 64
#define SLOPE 0.2f
#define EPS 1e-5f

typedef float f32x4 __attribute__((ext_vector_type(4)));
typedef short bf16x8 __attribute__((ext_vector_type(8)));
typedef unsigned short ushort;

__device__ __forceinline__ float lrelu(float x) { return x > 0.f ? x : SLOPE * x; }

// fp32 -> bf16 RNE
__device__ __forceinline__ ushort f2bf(float x) {
  union { float f; unsigned u; } c; c.f = x;
  unsigned r = c.u + 0x7FFFu + ((c.u >> 16) & 1u);
  return (ushort)(r >> 16);
}
__device__ __forceinline__ float bf2f(unsigned u) {
  return __uint_as_float(u << 16);
}
__device__ __forceinline__ uint4 cvt8(const float* p) {
  float4 f0 = *(const float4*)p;
  float4 f1 = *(const float4*)(p + 4);
  union { ushort us[8]; uint4 v; } u;
  u.us[0] = f2bf(f0.x); u.us[1] = f2bf(f0.y);
  u.us[2] = f2bf(f0.z); u.us[3] = f2bf(f0.w);
  u.us[4] = f2bf(f1.x); u.us[5] = f2bf(f1.y);
  u.us[6] = f2bf(f1.z); u.us[7] = f2bf(f1.w);
  return u.v;
}

// ---------------------------------------------------------------------------
// K0: fold weights + pack bf16 tables + deg histogram + Xb conversion.
// Block ranges: [0,577) weight folds; [577, 577+nbHist) histogram (persists
// each edge's within-node rank so edge_fused4 is atomic-free:
// slot = offs[src] + rank[e]); rest: Xb = bf16(X) (read 4x by node_gemm, so
// one-time conversion halves its X traffic and deletes its cvt8 VALU work).
// All B tables in MFMA B-FRAGMENT order (direct global reads, L2-resident):
//   element (outcol, k) -> idx = (((ch*8+nt)*4+quad)*16+l15)*8+jj,
//   nt=outcol>>4, l15=outcol&15, ch=k>>5, quad=(k>>3)&3, jj=k&7.
__global__ __launch_bounds__(128) void fold_pack(
    const float* __restrict__ Wq, const float* __restrict__ Wk,
    const float* __restrict__ We, const float* __restrict__ A1,
    const float* __restrict__ bq, const float* __restrict__ bk,
    const float* __restrict__ be, const float* __restrict__ b1,
    const float* __restrict__ Wn, const float* __restrict__ Wv,
    ushort* __restrict__ AfqP, ushort* __restrict__ AfkP,
    ushort* __restrict__ AfeP, float* __restrict__ bfold,
    ushort* __restrict__ WnP, ushort* __restrict__ WvP,
    const int* __restrict__ src, int* __restrict__ deg,
    int* __restrict__ rank, const float* __restrict__ X,
    ushort* __restrict__ Xb, int Nn, int E) {
  int r = blockIdx.x;
  int j = threadIdx.x;
  if (r < 128) {
    float acc = 0.f;
    for (int t = 0; t < 128; ++t) acc += Wq[r * 128 + t] * A1[t * 128 + j];
    int ch = r >> 5, quad = (r >> 3) & 3, jj = r & 7, nt = j >> 4, l15 = j & 15;
    AfqP[(((ch * 8 + nt) * 4 + quad) * 16 + l15) * 8 + jj] = f2bf(acc);
  } else if (r < 256) {
    int k = r - 128;
    float acc = 0.f;
    for (int t = 0; t < 128; ++t) acc += Wk[k * 128 + t] * A1[(128 + t) * 128 + j];
    int ch = k >> 5, quad = (k >> 3) & 3, jj = k & 7, nt = j >> 4, l15 = j & 15;
    AfkP[(((ch * 8 + nt) * 4 + quad) * 16 + l15) * 8 + jj] = f2bf(acc);
  } else if (r < 320) {
    int k = r - 256;  // [0,64)
    float acc = 0.f;
    for (int t = 0; t < 128; ++t) acc += We[k * 128 + t] * A1[(256 + t) * 128 + j];
    int ch = k >> 5, quad = (k >> 3) & 3, jj = k & 7, nt = j >> 4, l15 = j & 15;
    AfeP[(((ch * 8 + nt) * 4 + quad) * 16 + l15) * 8 + jj] = f2bf(acc);
  } else if (r == 320) {
    float acc = b1[j];
    for (int t = 0; t < 128; ++t) {
      acc += bq[t] * A1[t * 128 + j];
      acc += bk[t] * A1[(128 + t) * 128 + j];
      acc += be[t] * A1[(256 + t) * 128 + j];
    }
    bfold[j] = acc;
  } else if (r < 449) {
    int c = r - 321;
    int ch = j >> 5, quad = (j >> 3) & 3, jj = j & 7, nt = c >> 4, l15 = c & 15;
    WnP[(((ch * 8 + nt) * 4 + quad) * 16 + l15) * 8 + jj] = f2bf(Wn[j * 128 + c]);
  } else if (r < 577) {
    int c = r - 449;
    int ch = j >> 5, quad = (j >> 3) & 3, jj = j & 7, nt = c >> 4, l15 = c & 15;
    WvP[(((ch * 8 + nt) * 4 + quad) * 16 + l15) * 8 + jj] = f2bf(Wv[j * 128 + c]);
  } else {
    int rr = r - 577;
    int nbHist = (E + 127) >> 7;
    if (rr < nbHist) {
      int i = rr * 128 + j;
      if (i < E) rank[i] = atomicAdd(&deg[src[i]], 1);
    } else {
      size_t base = (size_t)(rr - nbHist) * 1024 + (size_t)j * 8;
      if (base < (size_t)Nn * 128)
        *(uint4*)(Xb + base) = cvt8(X + base);
    }
  }
}

// ---------------------------------------------------------------------------
// K1: node GEMMs via MFMA. ROUND-3 structure (4 dispatches via blockIdx.y,
// 128-row M-tile, B direct-from-global in fragment order). Round-4's
// single-dispatch fusion REGRESSED (+15us): parallelism beats traffic on
// this latency-bound pipeline -- DO NOT re-fuse.
// THIS ROUND: A staged from pre-converted bf16 Xb (no cvt8, half the bytes).
//  y=0: h = X@Wn+bn (fp32)              y=1: vb = bf16(X@Wv+bv)
//  y=2: q2p = bf16(X@Af_q) permuted     y=3: k2p = bf16(X@Af_k) permuted
__global__ __launch_bounds__(256, 2) void node_gemm_mfma(
    const ushort* __restrict__ Xb, const ushort* __restrict__ WnP,
    const ushort* __restrict__ WvP, const ushort* __restrict__ AfqP,
    const ushort* __restrict__ AfkP, const float* __restrict__ bn,
    const float* __restrict__ bv, float* __restrict__ h,
    ushort* __restrict__ vb, ushort* __restrict__ q2p,
    ushort* __restrict__ k2p, int Nn) {
  __shared__ ushort As[128 * 40];
  __shared__ float bS[128];
  const ushort* BP;
  const float* bb = nullptr;
  float* O = nullptr;
  ushort* Ob = nullptr;
  int mode;
  switch (blockIdx.y) {
    case 0: BP = WnP; bb = bn; O = h; mode = 0; break;
    case 1: BP = WvP; bb = bv; Ob = vb; mode = 1; break;
    case 2: BP = AfqP; Ob = q2p; mode = 2; break;
    default: BP = AfkP; Ob = k2p; mode = 2; break;
  }
  const int t = threadIdx.x;
  if (t < 128) bS[t] = bb ? bb[t] : 0.f;
  const int seg = t & 3, arow = t >> 2;  // arow in [0,64)
  const int m0 = blockIdx.x * 128;
  int rIdx[2];
#pragma unroll
  for (int l = 0; l < 2; ++l) rIdx[l] = min(m0 + arow + 64 * l, Nn - 1);
  uint4 avA[2];
#pragma unroll
  for (int l = 0; l < 2; ++l)
    avA[l] = *(const uint4*)(Xb + (size_t)rIdx[l] * 128 + seg * 8);
  f32x4 acc[2][8];
#pragma unroll
  for (int mt = 0; mt < 2; ++mt)
#pragma unroll
    for (int nt = 0; nt < 8; ++nt) acc[mt][nt] = (f32x4)(0.f);
  const int lane = t & 63, wv = t >> 6, l15 = lane & 15, quad = lane >> 4;
  for (int ch = 0; ch < 4; ++ch) {
#pragma unroll
    for (int l = 0; l < 2; ++l)
      *(uint4*)&As[(arow + 64 * l) * 40 + seg * 8] = avA[l];
    __syncthreads();
    if (ch < 3) {
      int o = (ch + 1) * 32 + seg * 8;
#pragma unroll
      for (int l = 0; l < 2; ++l)
        avA[l] = *(const uint4*)(Xb + (size_t)rIdx[l] * 128 + o);
    }
    bf16x8 af[2];
#pragma unroll
    for (int mt = 0; mt < 2; ++mt)
      af[mt] = *(const bf16x8*)&As[(wv * 32 + mt * 16 + l15) * 40 + quad * 8];
    // B fragments straight from global (fragment-ordered, L2-resident):
    const ushort* bp = BP + ((size_t)(ch * 8) * 64 + lane) * 8;
#pragma unroll
    for (int nt = 0; nt < 8; ++nt) {
      bf16x8 bfr = *(const bf16x8*)(bp + nt * 512);
#pragma unroll
      for (int mt = 0; mt < 2; ++mt)
        acc[mt][nt] =
            __builtin_amdgcn_mfma_f32_16x16x32_bf16(af[mt], bfr, acc[mt][nt], 0, 0, 0);
    }
    __syncthreads();
  }
#pragma unroll
  for (int mt = 0; mt < 2; ++mt) {
    int rowb = m0 + wv * 32 + mt * 16 + quad * 4;
#pragma unroll
    for (int nt = 0; nt < 8; ++nt) {
      int col = nt * 16 + l15;
      float b = bS[col];
#pragma unroll
      for (int r = 0; r < 4; ++r) {
        int rg = rowb + r;
        if (rg < Nn) {
          if (mode == 0)      O[(size_t)rg * 128 + col] = acc[mt][nt][r] + b;
          else if (mode == 1) Ob[(size_t)rg * 128 + col] = f2bf(acc[mt][nt][r] + b);
          else                Ob[(size_t)rg * 128 + l15 * 8 + nt] = f2bf(acc[mt][nt][r]);
        }
      }
    }
  }
}

// ---------------------------------------------------------------------------
// K2: streaming edge pipeline, 128 edges/block (M=32/wave), atomic-free CSR
// fill (slot = offs[src] + rank[e]) + per-block softmax partial.
// THIS ROUND: single-barrier schedule. As widened to hold BOTH 32-col EF
// chunks (row stride 88 ushorts = 176B -> b128 reads are 2-way bank aliased
// = free; chunk offset 48 ushorts = 96B keeps 16B alignment). All EF loaded
// up front, staged once, ONE barrier, then MFMA ch0+ch1 back to back.
// q2p/k2p gathers for mt=0 issued right after the barrier (latency hides
// under both MFMA chunks); mt=1 gathers grouped at its epilogue top.
// Removes: 2 barriers, the EF-ch1 stall, most of the gather stall.
// Occupancy/regalloc history: (256,3) natural VGPR no spill KNOWN GOOD;
//   (256,4) -> VGPR 64 + spills; (256,5) -> VGPR 48 + massive spills.
// Rule: min_waves>3 forces an allocator tier below natural and spills.
// Spill canary: WRITE_SIZE (~13MB clean).
__global__ __launch_bounds__(256, 3) void edge_fused4(
    const float* __restrict__ EF, const ushort* __restrict__ AfeP,
    const float* __restrict__ bfold, const float* __restrict__ A2,
    const float* __restrict__ b2, const ushort* __restrict__ q2p,
    const ushort* __restrict__ k2p, const int* __restrict__ src,
    const int* __restrict__ tgt, const int* __restrict__ offs,
    const int* __restrict__ rank,
    int2* __restrict__ cwt, float2* __restrict__ part, int E) {
  __shared__ ushort As[128 * 88];  // both chunks: [row][ch*48 + 0..31], pad
  __shared__ float A2s[8 * 128];   // transposed: A2s[h][d]
  __shared__ float bfS[128];
  __shared__ float b2s[8];
  __shared__ int sIdxS[128], sIdxT[128], sRank[128];
  __shared__ float redM[16], redS[16];
  const int t = threadIdx.x;
  const int e0 = blockIdx.x * 128;
  if (t < 128) {
    int ec = min(e0 + t, E - 1);
    sIdxS[t] = src[ec];
    sRank[t] = rank[ec];
    bfS[t] = bfold[t];
  } else {
    sIdxT[t - 128] = tgt[min(e0 + t - 128, E - 1)];
  }
  if (t < 8) b2s[t] = b2[t];
#pragma unroll
  for (int l = 0; l < 4; ++l) {
    int i = t + l * 256;  // A2 linear: d = i>>3, h = i&7
    A2s[(i & 7) * 128 + (i >> 3)] = A2[i];
  }
  const int seg = t & 3, arow = t >> 2;  // arow in [0,64)
  int ecl[2];
#pragma unroll
  for (int l = 0; l < 2; ++l) ecl[l] = min(e0 + arow + 64 * l, E - 1);
  const int lane = t & 63, wv = t >> 6, l15 = lane & 15, quad = lane >> 4;
  // load ALL EF cols (both chunks, both rows) and stage once
  {
    uint4 a0 = cvt8(EF + (size_t)ecl[0] * 64 + seg * 8);
    uint4 a1 = cvt8(EF + (size_t)ecl[1] * 64 + seg * 8);
    uint4 a2 = cvt8(EF + (size_t)ecl[0] * 64 + 32 + seg * 8);
    uint4 a3 = cvt8(EF + (size_t)ecl[1] * 64 + 32 + seg * 8);
    *(uint4*)&As[arow * 88 + seg * 8] = a0;
    *(uint4*)&As[(arow + 64) * 88 + seg * 8] = a1;
    *(uint4*)&As[arow * 88 + 48 + seg * 8] = a2;
    *(uint4*)&As[(arow + 64) * 88 + 48 + seg * 8] = a3;
  }
  f32x4 acc[2][8];
#pragma unroll
  for (int mt = 0; mt < 2; ++mt)
#pragma unroll
    for (int nt = 0; nt < 8; ++nt) acc[mt][nt] = (f32x4)(0.f);
  __syncthreads();  // the ONLY staging barrier

  // prefetch q/k gathers for mt=0 rows: latency hides under both MFMA chunks
  const int er0 = wv * 32 + quad * 4;
  uint4 qv0[4], kv0[4];
#pragma unroll
  for (int r = 0; r < 4; ++r) {
    qv0[r] = *(const uint4*)(q2p + (size_t)sIdxS[er0 + r] * 128 + l15 * 8);
    kv0[r] = *(const uint4*)(k2p + (size_t)sIdxT[er0 + r] * 128 + l15 * 8);
  }
  // MFMA chunk 0 then chunk 1 (no barriers: As read-only now)
#pragma unroll
  for (int ch = 0; ch < 2; ++ch) {
    bf16x8 af0 = *(const bf16x8*)&As[(wv * 32 + l15) * 88 + ch * 48 + quad * 8];
    bf16x8 af1 =
        *(const bf16x8*)&As[(wv * 32 + 16 + l15) * 88 + ch * 48 + quad * 8];
    const ushort* bp = AfeP + ((size_t)(ch * 8) * 64 + lane) * 8;
#pragma unroll
    for (int nt = 0; nt < 8; ++nt) {
      bf16x8 bfr = *(const bf16x8*)(bp + nt * 512);
      acc[0][nt] = __builtin_amdgcn_mfma_f32_16x16x32_bf16(af0, bfr, acc[0][nt], 0, 0, 0);
      acc[1][nt] = __builtin_amdgcn_mfma_f32_16x16x32_bf16(af1, bfr, acc[1][nt], 0, 0, 0);
    }
  }

  float bfv[8];
#pragma unroll
  for (int nt = 0; nt < 8; ++nt) bfv[nt] = bfS[nt * 16 + l15];
  // epilogue mt=0 (qv0/kv0 already in flight since before the MFMAs)
#pragma unroll
  for (int r = 0; r < 4; ++r) {
    const ushort* qs = (const ushort*)&qv0[r];
    const ushort* ks = (const ushort*)&kv0[r];
#pragma unroll
    for (int nt = 0; nt < 8; ++nt)
      acc[0][nt][r] =
          lrelu(acc[0][nt][r] + bf2f(qs[nt]) + bf2f(ks[nt]) + bfv[nt]);
  }
  // epilogue mt=1 (8 independent gathers issued together at loop top)
  {
    const int er1 = er0 + 16;
    uint4 qv1[4], kv1[4];
#pragma unroll
    for (int r = 0; r < 4; ++r) {
      qv1[r] = *(const uint4*)(q2p + (size_t)sIdxS[er1 + r] * 128 + l15 * 8);
      kv1[r] = *(const uint4*)(k2p + (size_t)sIdxT[er1 + r] * 128 + l15 * 8);
    }
#pragma unroll
    for (int r = 0; r < 4; ++r) {
      const ushort* qs = (const ushort*)&qv1[r];
      const ushort* ks = (const ushort*)&kv1[r];
#pragma unroll
      for (int nt = 0; nt < 8; ++nt)
        acc[1][nt][r] =
            lrelu(acc[1][nt][r] + bf2f(qs[nt]) + bf2f(ks[nt]) + bfv[nt]);
    }
  }
  // head stage: s = mean_h lrelu(hmid @ A2 + b2)
  float tacc[2][4];
#pragma unroll
  for (int mt = 0; mt < 2; ++mt)
#pragma unroll
    for (int r = 0; r < 4; ++r) tacc[mt][r] = 0.f;
  for (int hh = 0; hh < 8; ++hh) {
    float a2v[8];
#pragma unroll
    for (int nt = 0; nt < 8; ++nt) a2v[nt] = A2s[hh * 128 + nt * 16 + l15];
    float b2h = b2s[hh];
#pragma unroll
    for (int mt = 0; mt < 2; ++mt)
#pragma unroll
      for (int r = 0; r < 4; ++r) {
        float p = 0.f;
#pragma unroll
        for (int nt = 0; nt < 8; ++nt) p += acc[mt][nt][r] * a2v[nt];
        p += __shfl_xor(p, 1);
        p += __shfl_xor(p, 2);
        p += __shfl_xor(p, 4);
        p += __shfl_xor(p, 8);
        tacc[mt][r] += lrelu(p + b2h);
      }
  }
  // l15==0 lanes: 8 scores each -> CSR fill (atomic-free) + softmax partial
  if (l15 == 0) {
    float sc[8];
    float m = -1e30f;
#pragma unroll
    for (int mt = 0; mt < 2; ++mt)
#pragma unroll
      for (int r = 0; r < 4; ++r) {
        int i = mt * 4 + r;
        sc[i] = tacc[mt][r] * 0.125f;
        int e = e0 + wv * 32 + mt * 16 + quad * 4 + r;
        if (e < E) m = fmaxf(m, sc[i]);
      }
    float ssum = 0.f;
#pragma unroll
    for (int mt = 0; mt < 2; ++mt)
#pragma unroll
      for (int r = 0; r < 4; ++r) {
        int i = mt * 4 + r;
        int erow = wv * 32 + mt * 16 + quad * 4 + r;
        if (e0 + erow < E) {
          ssum += __expf(sc[i] - m);
          int j = offs[sIdxS[erow]] + sRank[erow];
          cwt[j] = make_int2(sIdxT[erow], __float_as_int(sc[i]));
        }
      }
    int rid = wv * 4 + quad;
    redM[rid] = m;
    redS[rid] = ssum;
  }
  __syncthreads();
  if (t == 0) {
    float M = redM[0], S = redS[0];
#pragma unroll
    for (int i = 1; i < 16; ++i) {
      float m2 = redM[i], s2 = redS[i];
      float Mn = fmaxf(M, m2);
      S = S * __expf(M - Mn) + s2 * __expf(m2 - Mn);
      M = Mn;
    }
    part[blockIdx.x] = make_float2(M, S);
  }
}

// ---------------------------------------------------------------------------
// K3: final reduce of per-block partials -> MS[0]=M, MS[1]=1/sum
__global__ __launch_bounds__(256) void softmax_final(
    const float2* __restrict__ part, int nPart, float* __restrict__ MS) {
  __shared__ float mS[256], sS[256];
  int tid = threadIdx.x;
  float m = -1e30f, sum = 0.f;
  for (int i = tid; i < nPart; i += 256) {
    float2 p = part[i];
    float M = fmaxf(m, p.x);
    sum = sum * __expf(m - M) + p.y * __expf(p.x - M);
    m = M;
  }
  mS[tid] = m;
  sS[tid] = sum;
  __syncthreads();
  for (int off = 128; off > 0; off >>= 1) {
    if (tid < off) {
      float m1 = mS[tid], s1 = sS[tid];
      float m2 = mS[tid + off], s2 = sS[tid + off];
      float M = fmaxf(m1, m2);
      mS[tid] = M;
      sS[tid] = s1 * __expf(m1 - M) + s2 * __expf(m2 - M);
    }
    __syncthreads();
  }
  if (tid == 0) {
    MS[0] = mS[0];
    MS[1] = 1.f / sS[0];
  }
}

// ---------------------------------------------------------------------------
// CSR scan (exclusive prefix over deg)
__global__ __launch_bounds__(256) void scan1(const int* __restrict__ deg,
                                             int* __restrict__ incl,
                                             int* __restrict__ bsum, int N) {
  __shared__ int sh[256];
  int tid = threadIdx.x;
  int i = blockIdx.x * 256 + tid;
  sh[tid] = (i < N) ? deg[i] : 0;
  __syncthreads();
  for (int off = 1; off < 256; off <<= 1) {
    int tv = (tid >= off) ? sh[tid - off] : 0;
    __syncthreads();
    sh[tid] += tv;
    __syncthreads();
  }
  if (i < N) incl[i] = sh[tid];
  if (tid == 255) bsum[blockIdx.x] = sh[255];
}

__global__ __launch_bounds__(256) void scan2(int* __restrict__ bsum, int nb) {
  __shared__ int sh[256];
  int tid = threadIdx.x;
  sh[tid] = (tid < nb) ? bsum[tid] : 0;
  __syncthreads();
  for (int off = 1; off < 256; off <<= 1) {
    int tv = (tid >= off) ? sh[tid - off] : 0;
    __syncthreads();
    sh[tid] += tv;
    __syncthreads();
  }
  if (tid < nb) bsum[tid] = sh[tid];
}

__global__ __launch_bounds__(256) void scan3(const int* __restrict__ deg,
                                             const int* __restrict__ incl,
                                             const int* __restrict__ bsum,
                                             int* __restrict__ offs, int N,
                                             int E) {
  int i = blockIdx.x * 256 + threadIdx.x;
  if (i >= N) return;
  int base = (blockIdx.x > 0) ? bsum[blockIdx.x - 1] : 0;
  int ex = incl[i] - deg[i] + base;
  offs[i] = ex;
  if (i == N - 1) offs[N] = E;
}

// ---------------------------------------------------------------------------
// K5: fused gather (bf16 v) + softmax-normalize + layernorm, unroll x4.
__global__ __launch_bounds__(256) void gather_ln(
    const int* __restrict__ offs, const int2* __restrict__ cwt,
    const ushort* __restrict__ vb, const float* __restrict__ MS,
    const float* __restrict__ gamma, const float* __restrict__ beta,
    float* __restrict__ y, int N) {
  int tid = threadIdx.x;
  int n = blockIdx.x * 4 + (tid >> 6);
  if (n >= N) return;  // wave-uniform
  int lane = tid & 63;
  float M = MS[0], inv = MS[1];
  int beg = offs[n], end = offs[n + 1];
  float a0 = 0.f, a1 = 0.f;
  int j = beg;
  for (; j + 4 <= end; j += 4) {
    int2 p0 = cwt[j], p1 = cwt[j + 1], p2 = cwt[j + 2], p3 = cwt[j + 3];
    unsigned u0 = *(const unsigned*)(vb + (size_t)p0.x * 128 + lane * 2);
    unsigned u1 = *(const unsigned*)(vb + (size_t)p1.x * 128 + lane * 2);
    unsigned u2 = *(const unsigned*)(vb + (size_t)p2.x * 128 + lane * 2);
    unsigned u3 = *(const unsigned*)(vb + (size_t)p3.x * 128 + lane * 2);
    float w0 = __expf(__int_as_float(p0.y) - M) * inv;
    float w1 = __expf(__int_as_float(p1.y) - M) * inv;
    float w2 = __expf(__int_as_float(p2.y) - M) * inv;
    float w3 = __expf(__int_as_float(p3.y) - M) * inv;
    a0 += w0 * bf2f(u0 & 0xffffu) + w1 * bf2f(u1 & 0xffffu) +
          w2 * bf2f(u2 & 0xffffu) + w3 * bf2f(u3 & 0xffffu);
    a1 += w0 * bf2f(u0 >> 16) + w1 * bf2f(u1 >> 16) + w2 * bf2f(u2 >> 16) +
          w3 * bf2f(u3 >> 16);
  }
  for (; j < end; ++j) {
    int2 p = cwt[j];
    float w = __expf(__int_as_float(p.y) - M) * inv;
    unsigned u = *(const unsigned*)(vb + (size_t)p.x * 128 + lane * 2);
    a0 += w * bf2f(u & 0xffffu);
    a1 += w * bf2f(u >> 16);
  }
  size_t base = (size_t)n * 128 + lane * 2;
  float2 hv = *(const float2*)(y + base);
  float y0 = hv.x + a0, y1 = hv.y + a1;
  float sum = y0 + y1, ssq = y0 * y0 + y1 * y1;
#pragma unroll
  for (int off = 1; off < 64; off <<= 1) {
    sum += __shfl_xor(sum, off);
    ssq += __shfl_xor(ssq, off);
  }
  float mu = sum * (1.f / 128.f);
  float var = ssq * (1.f / 128.f) - mu * mu;
  float rstd = rsqrtf(var + EPS);
  float2 g = *(const float2*)(gamma + lane * 2);
  float2 bt = *(const float2*)(beta + lane * 2);
  float2 out;
  out.x = g.x * (y0 - mu) * rstd + bt.x;
  out.y = g.y * (y1 - mu) * rstd + bt.y;
  *(float2*)(y + base) = out;
}

// ---------------------------------------------------------------------------
extern "C" void kernel_launch(void* const* d_in, const int* in_sizes, int n_in,
                              void* d_out, int out_size, void* d_ws,
                              size_t ws_size, hipStream_t stream) {
  const float* X  = (const float*)d_in[0];
  const float* EF = (const float*)d_in[1];
  const float* Wn = (const float*)d_in[2];
  const float* bn = (const float*)d_in[3];
  const float* Wq = (const float*)d_in[4];
  const float* bq = (const float*)d_in[5];
  const float* Wk = (const float*)d_in[6];
  const float* bk = (const float*)d_in[7];
  const float* Wv = (const float*)d_in[8];
  const float* bv = (const float*)d_in[9];
  const float* We = (const float*)d_in[10];
  const float* be = (const float*)d_in[11];
  const float* A1 = (const float*)d_in[12];
  const float* b1 = (const float*)d_in[13];
  const float* A2 = (const float*)d_in[14];
  const float* b2 = (const float*)d_in[15];
  const float* gamma = (const float*)d_in[16];
  const float* beta  = (const float*)d_in[17];
  const int* ei = (const int*)d_in[18];

  int N = in_sizes[0] / D;   // 50000
  int E = in_sizes[1] / DE;  // 400000
  const int* src = ei;
  const int* tgt = ei + E;

  float* h = (float*)d_out;  // h accumulated/normalized in place
  float* ws = (float*)d_ws;
  float2* part = (float2*)ws;                          // 4096 cap
  float* MS    = (float*)(part + 4096);                // 4
  float* bfold = MS + 4;                               // 128
  ushort* vb   = (ushort*)(bfold + 128);               // N*128 bf16
  ushort* q2p  = vb + (size_t)N * D;                   // N*128
  ushort* k2p  = q2p + (size_t)N * D;                  // N*128
  ushort* AfqP = k2p + (size_t)N * D;                  // 128*128
  ushort* AfkP = AfqP + 128 * 128;                     // 128*128
  ushort* AfeP = AfkP + 128 * 128;                     // 128*64
  ushort* WnP  = AfeP + 128 * 64;                      // 128*128
  ushort* WvP  = WnP + 128 * 128;                      // 128*128
  int* deg    = (int*)(WvP + 128 * 128);               // N
  int* incl   = deg + N;                               // N
  int* bsum   = incl + N;                              // 256
  int* rank   = bsum + 256;                            // E
  int* offs   = rank + E;                              // N+2
  int2* cwt   = (int2*)(offs + N + 2);                 // E
  ushort* Xb  = (ushort*)(cwt + E);                    // N*128 bf16

  int nbScan = (N + 255) / 256;          // 196 (<= 256)
  int nbEdge = (E + 127) / 128;          // 3125 (<= 4096 part cap)
  int nbHist = (E + 127) / 128;
  int nbXb   = (N * 128 + 1023) / 1024;  // 6250

  hipMemsetAsync(deg, 0, (size_t)N * sizeof(int), stream);
  fold_pack<<<577 + nbHist + nbXb, 128, 0, stream>>>(
      Wq, Wk, We, A1, bq, bk, be, b1, Wn, Wv, AfqP, AfkP, AfeP, bfold, WnP,
      WvP, src, deg, rank, X, Xb, N, E);
  scan1<<<nbScan, 256, 0, stream>>>(deg, incl, bsum, N);
  scan2<<<1, 256, 0, stream>>>(bsum, nbScan);
  scan3<<<nbScan, 256, 0, stream>>>(deg, incl, bsum, offs, N, E);
  node_gemm_mfma<<<dim3((N + 127) / 128, 4), 256, 0, stream>>>(
      Xb, WnP, WvP, AfqP, AfkP, bn, bv, h, vb, q2p, k2p, N);
  edge_fused4<<<nbEdge, 256, 0, stream>>>(EF, AfeP, bfold, A2, b2, q2p, k2p,
                                          src, tgt, offs, rank, cwt, part, E);
  softmax_final<<<1, 256, 0, stream>>>(part, nbEdge, MS);
  gather_ln<<<(N + 3) / 4, 256, 0, stream>>>(offs, cwt, vb, MS, gamma, beta, h,
                                             N);
}